// Round 6
// baseline (1374.053 us; speedup 1.0000x reference)
//
#include <hip/hip_runtime.h>
#include <cstdint>
#include <cstddef>

// RNG scheme for reproducing jax.random.uniform(jax.random.key(42), (8,2048,16,512)):
//   0: threefry_partitionable (counter = (0, i)), bits = out0 ^ out1   [verified passing]
#define RNG_SCHEME 0

#define N_TOK 16384      // B*T
#define DIM   1024       // D
#define NGRP  16         // V
#define NCODE 512        // K
#define GDIM  64         // d

typedef float v2f __attribute__((ext_vector_type(2)));

// ---------------- Threefry-2x32, key = (0, 42) ----------------
__device__ __forceinline__ uint2 threefry_0_42(uint32_t x0, uint32_t x1) {
  const uint32_t ks0 = 0u;
  const uint32_t ks1 = 42u;
  const uint32_t ks2 = 0x1BD11BDAu ^ 0u ^ 42u;
  x0 += ks0; x1 += ks1;
#define TF_R(r) { x0 += x1; x1 = (x1 << (r)) | (x1 >> (32 - (r))); x1 ^= x0; }
  TF_R(13) TF_R(15) TF_R(26) TF_R(6)
  x0 += ks1; x1 += ks2 + 1u;
  TF_R(17) TF_R(29) TF_R(16) TF_R(24)
  x0 += ks2; x1 += ks0 + 2u;
  TF_R(13) TF_R(15) TF_R(26) TF_R(6)
  x0 += ks0; x1 += ks1 + 3u;
  TF_R(17) TF_R(29) TF_R(16) TF_R(24)
  x0 += ks1; x1 += ks2 + 4u;
  TF_R(13) TF_R(15) TF_R(26) TF_R(6)
  x0 += ks2; x1 += ks0 + 5u;
#undef TF_R
  return make_uint2(x0, x1);
}

// u in [0,1) exactly as jax: (bits>>9 | 0x3f800000) bitcast - 1.0f
__device__ __forceinline__ float u_from_bits(uint32_t bits) {
  return __uint_as_float((bits >> 9) | 0x3f800000u) - 1.0f;
}

// gumbel = -log(-log(u+1e-8) + 1e-8), ops ordered as the reference.
// fp-monotone nondecreasing in bits (every step is monotone).
__device__ __forceinline__ float gumbel_from_bits(uint32_t bits) {
  float u = u_from_bits(bits);
  float w = (-logf(u + 1e-8f)) + 1e-8f;
  return -logf(w);
}

// monotone float->uint map: preserves total order for non-NaN; equal iff bit-identical
__device__ __forceinline__ uint32_t mono_u32(float z) {
  uint32_t b = __float_as_uint(z);
  return b ^ ((uint32_t)(((int32_t)b) >> 31) | 0x80000000u);
}

// ---------------- zero helper ----------------
__global__ __launch_bounds__(256) void k_zero(float* __restrict__ p, int n) {
  int i = blockIdx.x * 256 + threadIdx.x;
  if (i < n) p[i] = 0.f;
}

// ---------------- c2 table + per-group threshold ----------------
// c2tab[v][k] = |c_vk|^2 (same d4-ascending tree as the old in-kernel c2a).
// thrv[v] = 2*max_k|c_vk| + 0.01  (g-space exclusion threshold; the 0.01 slack
// dominates every fp rounding in the bound chain).
__global__ __launch_bounds__(512) void k_c2(const float* __restrict__ cb,
                                            float* __restrict__ c2tab,
                                            float* __restrict__ thrv) {
  const int v = blockIdx.x, k = threadIdx.x;  // 16 x 512
  const float* cp = cb + (size_t)(v * NCODE + k) * GDIM;
  float s = 0.f;
#pragma unroll 4
  for (int d4 = 0; d4 < 16; ++d4) {
    float4 c = *(const float4*)(cp + d4 * 4);
    s += c.x * c.x + c.y * c.y + c.z * c.z + c.w * c.w;
  }
  c2tab[v * NCODE + k] = s;
  float m = s;
#pragma unroll
  for (int off = 1; off < 64; off <<= 1) m = fmaxf(m, __shfl_xor(m, off, 64));
  __shared__ float pm[8];
  if ((k & 63) == 0) pm[k >> 6] = m;
  __syncthreads();
  if (k == 0) {
    float mm = pm[0];
#pragma unroll
    for (int w = 1; w < 8; ++w) mm = fmaxf(mm, pm[w]);
    thrv[v] = 2.0f * sqrtf(mm) + 0.01f;
  }
}

// ---------------- fp32 NT GEMM, 128x64 tile, double-buffered LDS ----------------
// C[M,N] = A[M,K] * B[N,K]^T + bias[N];  M=16384, N=K=1024. BK=16, 256 thr, 8x4/thr.
// v2 pipeline: register-stage tile kt+1's global loads BEFORE computing tile kt
// (HBM latency hides under ~1000 cyc of FMA), ds_write to the inactive buffer
// after compute, ONE barrier per K-step (was two). All FMA order / staging
// values bit-identical to the single-buffer version -> identical q bits.
// red (q2 epilogue scratch) overlays as[0]: dead after the kt=62 barrier.
__global__ __launch_bounds__(256) void gemm_nt(
    const float* __restrict__ A, const float* __restrict__ B,
    const float* __restrict__ bias, float* __restrict__ C,
    const float* __restrict__ cbk, const int* __restrict__ gidx,
    float* __restrict__ q2w)
{
  __shared__ float as[2][16 * 132];  // [k][m], stride 132
  __shared__ float bs[2][16 * 68];   // [k][n], stride 68
  float* red = &as[0][0];            // [128][16] overlay (2048 <= 2112 floats)

  const int tid = threadIdx.x;
  const int tx = tid & 15;           // n
  const int ty = tid >> 4;           // m
  const int m0 = blockIdx.x * 128;
  const int n0 = blockIdx.y * 64;

  // staging decomposition (identical addressing to the single-buffer version)
  const int am0 = tid >> 2;          // i=0 rows 0..63
  const int am1 = (tid + 256) >> 2;  // i=1 rows 64..127
  const int ak4 = tid & 3;
  const int bn_l = tid >> 2, bk4 = tid & 3;

  float4 a4_0, a4_1, b4;

#define LOAD_TILE(kt_) {                                                        \
    if (gidx) {                                                                 \
      int vp = (kt_) >> 2;                                                      \
      int row0 = gidx[(m0 + am0) * NGRP + vp];                                  \
      int row1 = gidx[(m0 + am1) * NGRP + vp];                                  \
      a4_0 = *(const float4*)(cbk + ((size_t)(vp * NCODE + row0) * GDIM + ((kt_) & 3) * 16 + ak4 * 4)); \
      a4_1 = *(const float4*)(cbk + ((size_t)(vp * NCODE + row1) * GDIM + ((kt_) & 3) * 16 + ak4 * 4)); \
    } else {                                                                    \
      a4_0 = *(const float4*)(A + ((size_t)(m0 + am0) * DIM + (kt_) * 16 + ak4 * 4)); \
      a4_1 = *(const float4*)(A + ((size_t)(m0 + am1) * DIM + (kt_) * 16 + ak4 * 4)); \
    }                                                                           \
    b4 = *(const float4*)(B + ((size_t)(n0 + bn_l) * DIM + (kt_) * 16 + bk4 * 4)); \
  }

#define STORE_TILE(buf_) {                                                      \
    as[buf_][(ak4 * 4 + 0) * 132 + am0] = a4_0.x;                               \
    as[buf_][(ak4 * 4 + 1) * 132 + am0] = a4_0.y;                               \
    as[buf_][(ak4 * 4 + 2) * 132 + am0] = a4_0.z;                               \
    as[buf_][(ak4 * 4 + 3) * 132 + am0] = a4_0.w;                               \
    as[buf_][(ak4 * 4 + 0) * 132 + am1] = a4_1.x;                               \
    as[buf_][(ak4 * 4 + 1) * 132 + am1] = a4_1.y;                               \
    as[buf_][(ak4 * 4 + 2) * 132 + am1] = a4_1.z;                               \
    as[buf_][(ak4 * 4 + 3) * 132 + am1] = a4_1.w;                               \
    bs[buf_][(bk4 * 4 + 0) * 68 + bn_l] = b4.x;                                 \
    bs[buf_][(bk4 * 4 + 1) * 68 + bn_l] = b4.y;                                 \
    bs[buf_][(bk4 * 4 + 2) * 68 + bn_l] = b4.z;                                 \
    bs[buf_][(bk4 * 4 + 3) * 68 + bn_l] = b4.w;                                 \
  }

  float acc[8][4] = {};

  LOAD_TILE(0)
  STORE_TILE(0)
  __syncthreads();

  for (int kt = 0; kt < 64; ++kt) {
    const int cur = kt & 1;
    if (kt < 63) LOAD_TILE(kt + 1)          // issue next-tile loads early
#pragma unroll
    for (int k = 0; k < 16; ++k) {
      float4 a0 = *(const float4*)&as[cur][k * 132 + ty * 8];
      float4 a1 = *(const float4*)&as[cur][k * 132 + ty * 8 + 4];
      float4 b0 = *(const float4*)&bs[cur][k * 68 + tx * 4];
      float av[8] = {a0.x, a0.y, a0.z, a0.w, a1.x, a1.y, a1.z, a1.w};
      float bv[4] = {b0.x, b0.y, b0.z, b0.w};
#pragma unroll
      for (int r = 0; r < 8; ++r)
#pragma unroll
        for (int j = 0; j < 4; ++j) acc[r][j] += av[r] * bv[j];
    }
    if (kt < 63) {
      STORE_TILE(cur ^ 1)                   // write-other-buffer: race-free
      __syncthreads();                      // single barrier per K-step
    }
  }
#undef LOAD_TILE
#undef STORE_TILE

  const float4 bb = *(const float4*)(bias + n0 + tx * 4);
#pragma unroll
  for (int r = 0; r < 8; ++r) {
    const int m = m0 + ty * 8 + r;
    float4 c;
    c.x = acc[r][0] + bb.x; c.y = acc[r][1] + bb.y;
    c.z = acc[r][2] + bb.z; c.w = acc[r][3] + bb.w;
    *(float4*)(C + (size_t)m * DIM + n0 + tx * 4) = c;
    // red overlays as[0]: last read of as[0] was kt=62, sealed by its barrier.
    if (q2w) red[(ty * 8 + r) * 16 + tx] = c.x * c.x + c.y * c.y + c.z * c.z + c.w * c.w;
  }
  if (q2w) {
    __syncthreads();
    if (tid < 128) {
      float s = 0.f;
#pragma unroll
      for (int x = 0; x < 16; ++x) s += red[tid * 16 + x];
      q2w[(size_t)(m0 + tid) * NGRP + blockIdx.y] = s;
    }
  }
}

// ---------------- candidate scoring helper (exact z) ----------------
__device__ __forceinline__ unsigned long long cand_key(
    const float* __restrict__ qp, const float* __restrict__ cp,
    float c2k, float q2v, uint32_t bits, int k)
{
  float acc = 0.f;
#pragma unroll 4
  for (int d4 = 0; d4 < 16; ++d4) {
    float4 qv = *(const float4*)(qp + d4 * 4);
    float4 cv = *(const float4*)(cp + d4 * 4);
    acc += qv.x * cv.x + qv.y * cv.y + qv.z * cv.z + qv.w * cv.w;
  }
  float g = gumbel_from_bits(bits);
  float z = (-sqrtf(fmaxf((q2v + c2k) - 2.0f * acc, 0.0f))) + g;
  return ((unsigned long long)mono_u32(z) << 32) | (uint32_t)(1023 - k);
}

// ---------------- K2: gumbel-bound candidate filter + exact argmax ----------------
// grid (2048, 16), 256 thr. Block = 8 tokens x group v; thread owns codes tid, tid+256.
//
// Soundness: |c_vk| <= Cmax_v  =>  d_k in [|q|-Cmax, |q|+Cmax]  (triangle ineq).
// Hence any k with g_k < max_g - 2*Cmax cannot win argmax(-d_k + g_k); slack
// 0.01 in g-space covers all fp rounding. g is fp-monotone in the threefry
// bits, so max_g per token = g(max bits) -- NO logf needed for the filter.
// The threshold is inverted into u-space once per token (u* = g^-1(max_g-THR),
// minus 1e-6 to stay conservative where g is coarsely quantized near u=1).
// Surviving candidates (~1.03/token) get the exact dot/sqrt/gumbel evaluation
// and a packed-u64 argmax (first-index tie-break == jnp.argmax).
__global__ __launch_bounds__(256) void k2_select(
    const float* __restrict__ q, const float* __restrict__ q2w,
    const float* __restrict__ cb, const float* __restrict__ c2tab,
    const float* __restrict__ thrv, float* __restrict__ counts,
    int* __restrict__ idxw)
{
  const int tid = threadIdx.x;
  const int tg = blockIdx.x;     // 0..2047
  const int v  = blockIdx.y;     // 0..15
  const int b_lo = tg >> 9;      // 0..3
  const int tq = tg & 511;       // 0..511
  const int k0 = tid, k1 = tid + 256;
  const int lane = tid & 63, wv = tid >> 6;

  __shared__ float redf[4][8];
  __shared__ float ustarS[8];
  __shared__ unsigned long long redk[4][8];

  // phase A: threefry bits for my 2 codes x 8 tokens (exact stream)
  uint32_t bits0[8], bits1[8];
#pragma unroll
  for (int tk = 0; tk < 8; ++tk) {
    const int tok = (b_lo + 4 * (tk & 1)) * 2048 + tq * 4 + (tk >> 1);
    const uint32_t base = ((uint32_t)(tok * NGRP + v)) << 9;
    uint2 r0 = threefry_0_42(0u, base + (uint32_t)k0);
    uint2 r1 = threefry_0_42(0u, base + (uint32_t)k1);
    bits0[tk] = r0.x ^ r0.y;
    bits1[tk] = r1.x ^ r1.y;
  }

  // phase B: per-token max bits (== max u == max g, all fp-monotone)
#pragma unroll
  for (int tk = 0; tk < 8; ++tk) {
    uint32_t m = bits0[tk] > bits1[tk] ? bits0[tk] : bits1[tk];
#pragma unroll
    for (int off = 1; off < 64; off <<= 1) {
      uint32_t o = __shfl_xor(m, off, 64);
      if (o > m) m = o;
    }
    if (lane == 0) redf[wv][tk] = __uint_as_float(m);
  }
  __syncthreads();

  // phase C: u* = g^-1(gmax - THR_v) - 1e-6, one token per low thread
  if (tid < 8) {
    uint32_t m = __float_as_uint(redf[0][tid]);
#pragma unroll
    for (int w = 1; w < 4; ++w) {
      uint32_t o = __float_as_uint(redf[w][tid]);
      if (o > m) m = o;
    }
    const float gmax = gumbel_from_bits(m);
    const float inner = gmax - thrv[v];
    const float wstar = expf(-inner) - 1e-8f;   // > 0 since inner <= ~16
    const float ustar = expf(-wstar) - 1e-8f - 1e-6f;
    ustarS[tid] = ustar;
  }
  __syncthreads();

  // phase D: candidates evaluate exact z; packed-u64 argmax
#pragma unroll 1
  for (int tk = 0; tk < 8; ++tk) {
    const int tok = (b_lo + 4 * (tk & 1)) * 2048 + tq * 4 + (tk >> 1);
    const float ustar = ustarS[tk];
    const bool c0 = u_from_bits(bits0[tk]) >= ustar;
    const bool c1 = u_from_bits(bits1[tk]) >= ustar;
    unsigned long long K = 0ull;
    if (c0 | c1) {
      const float q2v = q2w[tok * NGRP + v];
      const float* qp = q + (size_t)tok * DIM + v * GDIM;
      if (c0) {
        unsigned long long t = cand_key(qp, cb + (size_t)(v * NCODE + k0) * GDIM,
                                        c2tab[v * NCODE + k0], q2v, bits0[tk], k0);
        if (t > K) K = t;
      }
      if (c1) {
        unsigned long long t = cand_key(qp, cb + (size_t)(v * NCODE + k1) * GDIM,
                                        c2tab[v * NCODE + k1], q2v, bits1[tk], k1);
        if (t > K) K = t;
      }
    }
#pragma unroll
    for (int off = 1; off < 64; off <<= 1) {
      unsigned long long O = __shfl_xor(K, off, 64);
      if (O > K) K = O;
    }
    if (lane == 0) redk[wv][tk] = K;
  }
  __syncthreads();

  if (tid < 8) {
    unsigned long long K = redk[0][tid];
#pragma unroll
    for (int w = 1; w < 4; ++w) { unsigned long long O = redk[w][tid]; if (O > K) K = O; }
    // fi in [0,511] whenever any candidate survived (always true: the max-bits
    // lane passes its own filter). '& 511' hardens the impossible K==0 path so
    // it cannot become an OOB write (would surface as absmax fail instead).
    const int fi = (1023 - (int)(K & 0xFFFFFFFFu)) & 511;
    const int tok = (b_lo + 4 * (tid & 1)) * 2048 + tq * 4 + (tid >> 1);
    idxw[tok * NGRP + v] = fi;
    atomicAdd(&counts[v * NCODE + fi], 1.0f);
  }
}

// ---------------- targets ----------------
__global__ __launch_bounds__(256) void k_targets(const int* __restrict__ idxw, float* __restrict__ out) {
  int bt = blockIdx.x * 256 + threadIdx.x;  // 0..16383
  const int* p = idxw + bt * NGRP;
  int s = 0;
#pragma unroll
  for (int v = 0; v < NGRP; ++v) s += p[v] * (v * NCODE);
  out[bt] = (float)s;
}

// ---------------- diversity loss ----------------
__global__ __launch_bounds__(512) void k_losses(const float* __restrict__ counts, float* __restrict__ out) {
  __shared__ float partial[8];
  const int k = threadIdx.x;           // 0..511
  const int lane = k & 63, wv = k >> 6;
  const float invN = 1.0f / 16384.0f;  // pow2: identical to division
  const float logK = logf(512.0f);
  float total = 0.f;
  for (int v = 0; v < NGRP; ++v) {
    float p = counts[v * NCODE + k] * invN;
    float term = p * logf(p + 1e-8f);
    float s = term;
#pragma unroll
    for (int off = 1; off < 64; off <<= 1) s += __shfl_xor(s, off, 64);
    if (lane == 0) partial[wv] = s;
    __syncthreads();
    if (k == 0) {
      float t = 0.f;
#pragma unroll
      for (int w = 0; w < 8; ++w) t += partial[w];
      float ent = -t;
      total += ent / logK;
    }
    __syncthreads();
  }
  if (k == 0) out[0] = 0.1f * (-(total / 16.0f));
}

// ---------------- launch ----------------
extern "C" void kernel_launch(void* const* d_in, const int* in_sizes, int n_in,
                              void* d_out, int out_size, void* d_ws, size_t ws_size,
                              hipStream_t stream) {
  const float* features  = (const float*)d_in[0];  // (8,2048,1024)
  const float* codebooks = (const float*)d_in[1];  // (16,512,64)
  const float* Wq   = (const float*)d_in[2];       // (1024,1024)
  const float* bq   = (const float*)d_in[3];       // (1024)
  const float* Wout = (const float*)d_in[4];       // (1024,1024)
  const float* bout = (const float*)d_in[5];       // (1024)

  float* out = (float*)d_out;
  float* quantized = out;                 // 16,777,216
  float* targets   = out + 16777216;      // 16,384
  float* losses    = out + 16793600;      // 1

  float* ws     = (float*)d_ws;
  float* q      = ws;                     // 16,777,216 f
  float* q2w    = ws + 16777216;          // 262,144 f
  float* counts = ws + 17039360;          // 8,192 f
  int*   idxw   = (int*)(ws + 17047552);  // 262,144 i  (total 69.2 MB)

  // c2 table + thresholds live in the quantized output region as scratch;
  // k2 is the only consumer, and gemm2 (last kernel) overwrites the region.
  float* c2tab = quantized;               // 8,192 f
  float* thrv  = quantized + 8192;        // 16 f

  hipLaunchKernelGGL(k_zero, dim3(32), dim3(256), 0, stream, counts, NGRP * NCODE);
  hipLaunchKernelGGL(k_c2, dim3(16), dim3(512), 0, stream, codebooks, c2tab, thrv);
  hipLaunchKernelGGL(gemm_nt, dim3(128, 16), dim3(256), 0, stream,
                     features, Wq, bq, q, (const float*)nullptr, (const int*)nullptr, q2w);
  hipLaunchKernelGGL(k2_select, dim3(2048, 16), dim3(256), 0, stream,
                     q, q2w, codebooks, c2tab, thrv, counts, idxw);
  hipLaunchKernelGGL(k_targets, dim3(64), dim3(256), 0, stream, idxw, targets);
  hipLaunchKernelGGL(k_losses, dim3(1), dim3(512), 0, stream, counts, losses);
  hipLaunchKernelGGL(gemm_nt, dim3(128, 16), dim3(256), 0, stream,
                     (const float*)nullptr, Wout, bout, quantized, codebooks, idxw,
                     (float*)nullptr);
}

// Round 7
// 1309.404 us; speedup vs baseline: 1.0494x; 1.0494x over previous
//
#include <hip/hip_runtime.h>
#include <cstdint>
#include <cstddef>

// RNG scheme for reproducing jax.random.uniform(jax.random.key(42), (8,2048,16,512)):
//   0: threefry_partitionable (counter = (0, i)), bits = out0 ^ out1   [verified passing]
#define RNG_SCHEME 0

#define N_TOK 16384      // B*T
#define DIM   1024       // D
#define NGRP  16         // V
#define NCODE 512        // K
#define GDIM  64         // d

// ---------------- Threefry-2x32, key = (0, 42) ----------------
__device__ __forceinline__ uint2 threefry_0_42(uint32_t x0, uint32_t x1) {
  const uint32_t ks0 = 0u;
  const uint32_t ks1 = 42u;
  const uint32_t ks2 = 0x1BD11BDAu ^ 0u ^ 42u;
  x0 += ks0; x1 += ks1;
#define TF_R(r) { x0 += x1; x1 = (x1 << (r)) | (x1 >> (32 - (r))); x1 ^= x0; }
  TF_R(13) TF_R(15) TF_R(26) TF_R(6)
  x0 += ks1; x1 += ks2 + 1u;
  TF_R(17) TF_R(29) TF_R(16) TF_R(24)
  x0 += ks2; x1 += ks0 + 2u;
  TF_R(13) TF_R(15) TF_R(26) TF_R(6)
  x0 += ks0; x1 += ks1 + 3u;
  TF_R(17) TF_R(29) TF_R(16) TF_R(24)
  x0 += ks1; x1 += ks2 + 4u;
  TF_R(13) TF_R(15) TF_R(26) TF_R(6)
  x0 += ks2; x1 += ks0 + 5u;
#undef TF_R
  return make_uint2(x0, x1);
}

// u in [0,1) exactly as jax: (bits>>9 | 0x3f800000) bitcast - 1.0f
__device__ __forceinline__ float u_from_bits(uint32_t bits) {
  return __uint_as_float((bits >> 9) | 0x3f800000u) - 1.0f;
}

// gumbel = -log(-log(u+1e-8) + 1e-8), ops ordered as the reference.
// fp-monotone nondecreasing in bits (every step is monotone).
__device__ __forceinline__ float gumbel_from_bits(uint32_t bits) {
  float u = u_from_bits(bits);
  float w = (-logf(u + 1e-8f)) + 1e-8f;
  return -logf(w);
}

// monotone float->uint map: preserves total order for non-NaN; equal iff bit-identical
__device__ __forceinline__ uint32_t mono_u32(float z) {
  uint32_t b = __float_as_uint(z);
  return b ^ ((uint32_t)(((int32_t)b) >> 31) | 0x80000000u);
}

// ---------------- zero helper ----------------
__global__ __launch_bounds__(256) void k_zero(float* __restrict__ p, int n) {
  int i = blockIdx.x * 256 + threadIdx.x;
  if (i < n) p[i] = 0.f;
}

// ---------------- c2 table + per-group threshold ----------------
// c2tab[v][k] = |c_vk|^2 (same d4-ascending tree as the old in-kernel c2a).
// thrv[v] = 2*max_k|c_vk| + 0.01  (g-space exclusion threshold; the 0.01 slack
// dominates every fp rounding in the bound chain).
__global__ __launch_bounds__(512) void k_c2(const float* __restrict__ cb,
                                            float* __restrict__ c2tab,
                                            float* __restrict__ thrv) {
  const int v = blockIdx.x, k = threadIdx.x;  // 16 x 512
  const float* cp = cb + (size_t)(v * NCODE + k) * GDIM;
  float s = 0.f;
#pragma unroll 4
  for (int d4 = 0; d4 < 16; ++d4) {
    float4 c = *(const float4*)(cp + d4 * 4);
    s += c.x * c.x + c.y * c.y + c.z * c.z + c.w * c.w;
  }
  c2tab[v * NCODE + k] = s;
  float m = s;
#pragma unroll
  for (int off = 1; off < 64; off <<= 1) m = fmaxf(m, __shfl_xor(m, off, 64));
  __shared__ float pm[8];
  if ((k & 63) == 0) pm[k >> 6] = m;
  __syncthreads();
  if (k == 0) {
    float mm = pm[0];
#pragma unroll
    for (int w = 1; w < 8; ++w) mm = fmaxf(mm, pm[w]);
    thrv[v] = 2.0f * sqrtf(mm) + 0.01f;
  }
}

// ---------------- fp32 NT GEMM (round-5 verbatim: 128x64 tile, 8x4/thr) ----------
// Single-buffer, two barriers per K-step. Measured 445 us / 44 VGPR / occ 46%.
// DO NOT register-stage prefetch across the unrolled compute loop: measured
// 124 VGPR -> occ 21% -> 560 us (round-6 failure).
__global__ __launch_bounds__(256) void gemm_nt(
    const float* __restrict__ A, const float* __restrict__ B,
    const float* __restrict__ bias, float* __restrict__ C,
    const float* __restrict__ cbk, const int* __restrict__ gidx,
    float* __restrict__ q2w)
{
  __shared__ float as[16 * 132];   // [k][m], stride 132 (pad, keeps 16B align)
  __shared__ float bs[16 * 68];    // [k][n], stride 68
  __shared__ float red[128 * 16];  // q2 reduction scratch

  const int tid = threadIdx.x;
  const int tx = tid & 15;         // n
  const int ty = tid >> 4;         // m
  const int m0 = blockIdx.x * 128;
  const int n0 = blockIdx.y * 64;

  float acc[8][4] = {};

  for (int kt = 0; kt < 64; ++kt) {
    __syncthreads();
#pragma unroll
    for (int i = 0; i < 2; ++i) {
      int f = tid + 256 * i;
      int m_l = f >> 2, k4 = f & 3;
      const float* src;
      if (gidx) {
        int vp = kt >> 2;
        int row = gidx[(m0 + m_l) * NGRP + vp];
        src = cbk + ((size_t)(vp * NCODE + row) * GDIM + (kt & 3) * 16 + k4 * 4);
      } else {
        src = A + ((size_t)(m0 + m_l) * DIM + kt * 16 + k4 * 4);
      }
      float4 a4 = *(const float4*)src;
      as[(k4 * 4 + 0) * 132 + m_l] = a4.x;
      as[(k4 * 4 + 1) * 132 + m_l] = a4.y;
      as[(k4 * 4 + 2) * 132 + m_l] = a4.z;
      as[(k4 * 4 + 3) * 132 + m_l] = a4.w;
    }
    {
      int n_l = tid >> 2, k4 = tid & 3;
      float4 b4 = *(const float4*)(B + ((size_t)(n0 + n_l) * DIM + kt * 16 + k4 * 4));
      bs[(k4 * 4 + 0) * 68 + n_l] = b4.x;
      bs[(k4 * 4 + 1) * 68 + n_l] = b4.y;
      bs[(k4 * 4 + 2) * 68 + n_l] = b4.z;
      bs[(k4 * 4 + 3) * 68 + n_l] = b4.w;
    }
    __syncthreads();
#pragma unroll
    for (int k = 0; k < 16; ++k) {
      float4 a0 = *(const float4*)&as[k * 132 + ty * 8];
      float4 a1 = *(const float4*)&as[k * 132 + ty * 8 + 4];
      float4 b0 = *(const float4*)&bs[k * 68 + tx * 4];
      float av[8] = {a0.x, a0.y, a0.z, a0.w, a1.x, a1.y, a1.z, a1.w};
      float bv[4] = {b0.x, b0.y, b0.z, b0.w};
#pragma unroll
      for (int r = 0; r < 8; ++r)
#pragma unroll
        for (int j = 0; j < 4; ++j) acc[r][j] += av[r] * bv[j];
    }
  }

  const float4 bb = *(const float4*)(bias + n0 + tx * 4);
#pragma unroll
  for (int r = 0; r < 8; ++r) {
    const int m = m0 + ty * 8 + r;
    float4 c;
    c.x = acc[r][0] + bb.x; c.y = acc[r][1] + bb.y;
    c.z = acc[r][2] + bb.z; c.w = acc[r][3] + bb.w;
    *(float4*)(C + (size_t)m * DIM + n0 + tx * 4) = c;
    if (q2w) red[(ty * 8 + r) * 16 + tx] = c.x * c.x + c.y * c.y + c.z * c.z + c.w * c.w;
  }
  if (q2w) {
    __syncthreads();
    if (tid < 128) {
      float s = 0.f;
#pragma unroll
      for (int x = 0; x < 16; ++x) s += red[tid * 16 + x];
      q2w[(size_t)(m0 + tid) * NGRP + blockIdx.y] = s;
    }
  }
}

// ---------------- candidate scoring helper (exact z) ----------------
__device__ __forceinline__ unsigned long long cand_key(
    const float* __restrict__ qp, const float* __restrict__ cp,
    float c2k, float q2v, uint32_t bits, int k)
{
  float acc = 0.f;
#pragma unroll 4
  for (int d4 = 0; d4 < 16; ++d4) {
    float4 qv = *(const float4*)(qp + d4 * 4);
    float4 cv = *(const float4*)(cp + d4 * 4);
    acc += qv.x * cv.x + qv.y * cv.y + qv.z * cv.z + qv.w * cv.w;
  }
  float g = gumbel_from_bits(bits);
  float z = (-sqrtf(fmaxf((q2v + c2k) - 2.0f * acc, 0.0f))) + g;
  return ((unsigned long long)mono_u32(z) << 32) | (uint32_t)(1023 - k);
}

// ---------------- K2 v5: wave-per-token, barrier-free ----------------
// grid (4096, 16), 256 thr = 4 waves. Wave wv owns token blockIdx.x*4+wv for
// group v; lane owns codes k = lane + 64*i, i=0..7. All reductions are 64-lane
// shfl butterflies: NO __syncthreads, NO LDS.
//
// Soundness (unchanged from round-5, verified passing): any k with
// g_k < max_g - (2*Cmax_v + 0.01) cannot win argmax(-d_k + g_k); g is
// fp-monotone in threefry bits so the filter runs in u32/u-space with zero
// transcendentals; ustar = g^-1(gmax - THR_v) - 1e-6 (conservative vs the
// 2^-23 u-granularity). Survivors (~1/token) take the exact dot/sqrt/gumbel
// path; packed-u64 argmax == jnp.argmax first-index semantics.
__global__ __launch_bounds__(256) void k2_select(
    const float* __restrict__ q, const float* __restrict__ q2w,
    const float* __restrict__ cb, const float* __restrict__ c2tab,
    const float* __restrict__ thrv, float* __restrict__ counts,
    int* __restrict__ idxw)
{
  const int tid = threadIdx.x;
  const int lane = tid & 63, wv = tid >> 6;
  const int v   = blockIdx.y;                  // 0..15
  const int tok = blockIdx.x * 4 + wv;         // 0..16383

  // phase A: threefry bits for my 8 codes (exact stream: ctr = base + k)
  const uint32_t base = ((uint32_t)(tok * NGRP + v)) << 9;
  uint32_t bits[8];
#pragma unroll
  for (int i = 0; i < 8; ++i) {
    uint2 r = threefry_0_42(0u, base + (uint32_t)(lane + 64 * i));
    bits[i] = r.x ^ r.y;
  }

  // phase B: wave max of bits (== max u == max g, fp-monotone)
  uint32_t m = bits[0];
#pragma unroll
  for (int i = 1; i < 8; ++i) m = bits[i] > m ? bits[i] : m;
#pragma unroll
  for (int off = 1; off < 64; off <<= 1) {
    uint32_t o = __shfl_xor(m, off, 64);
    if (o > m) m = o;
  }

  // phase C: u* threshold (wave-uniform; every lane computes it, no broadcast needed)
  const float gmax = gumbel_from_bits(m);
  const float inner = gmax - thrv[v];
  const float wstar = expf(-inner) - 1e-8f;    // > 0 since inner <= ~16
  const float ustar = expf(-wstar) - 1e-8f - 1e-6f;

  // phase D: surviving candidates evaluate exact z; packed-u64 wave argmax
  const float q2v = q2w[tok * NGRP + v];
  const float* qp = q + (size_t)tok * DIM + v * GDIM;
  unsigned long long K = 0ull;
#pragma unroll 1
  for (int i = 0; i < 8; ++i) {
    if (u_from_bits(bits[i]) >= ustar) {
      const int k = lane + 64 * i;
      unsigned long long t = cand_key(qp, cb + (size_t)(v * NCODE + k) * GDIM,
                                      c2tab[v * NCODE + k], q2v, bits[i], k);
      if (t > K) K = t;
    }
  }
#pragma unroll
  for (int off = 1; off < 64; off <<= 1) {
    unsigned long long O = __shfl_xor(K, off, 64);
    if (O > K) K = O;
  }

  if (lane == 0) {
    // fi in [0,511] always (max-bits lane passes its own filter); '&511'
    // hardens the impossible K==0 path against an OOB write.
    const int fi = (1023 - (int)(K & 0xFFFFFFFFu)) & 511;
    idxw[tok * NGRP + v] = fi;
    atomicAdd(&counts[v * NCODE + fi], 1.0f);
  }
}

// ---------------- targets ----------------
__global__ __launch_bounds__(256) void k_targets(const int* __restrict__ idxw, float* __restrict__ out) {
  int bt = blockIdx.x * 256 + threadIdx.x;  // 0..16383
  const int* p = idxw + bt * NGRP;
  int s = 0;
#pragma unroll
  for (int v = 0; v < NGRP; ++v) s += p[v] * (v * NCODE);
  out[bt] = (float)s;
}

// ---------------- diversity loss ----------------
__global__ __launch_bounds__(512) void k_losses(const float* __restrict__ counts, float* __restrict__ out) {
  __shared__ float partial[8];
  const int k = threadIdx.x;           // 0..511
  const int lane = k & 63, wv = k >> 6;
  const float invN = 1.0f / 16384.0f;  // pow2: identical to division
  const float logK = logf(512.0f);
  float total = 0.f;
  for (int v = 0; v < NGRP; ++v) {
    float p = counts[v * NCODE + k] * invN;
    float term = p * logf(p + 1e-8f);
    float s = term;
#pragma unroll
    for (int off = 1; off < 64; off <<= 1) s += __shfl_xor(s, off, 64);
    if (lane == 0) partial[wv] = s;
    __syncthreads();
    if (k == 0) {
      float t = 0.f;
#pragma unroll
      for (int w = 0; w < 8; ++w) t += partial[w];
      float ent = -t;
      total += ent / logK;
    }
    __syncthreads();
  }
  if (k == 0) out[0] = 0.1f * (-(total / 16.0f));
}

// ---------------- launch ----------------
extern "C" void kernel_launch(void* const* d_in, const int* in_sizes, int n_in,
                              void* d_out, int out_size, void* d_ws, size_t ws_size,
                              hipStream_t stream) {
  const float* features  = (const float*)d_in[0];  // (8,2048,1024)
  const float* codebooks = (const float*)d_in[1];  // (16,512,64)
  const float* Wq   = (const float*)d_in[2];       // (1024,1024)
  const float* bq   = (const float*)d_in[3];       // (1024)
  const float* Wout = (const float*)d_in[4];       // (1024,1024)
  const float* bout = (const float*)d_in[5];       // (1024)

  float* out = (float*)d_out;
  float* quantized = out;                 // 16,777,216
  float* targets   = out + 16777216;      // 16,384
  float* losses    = out + 16793600;      // 1

  float* ws     = (float*)d_ws;
  float* q      = ws;                     // 16,777,216 f
  float* q2w    = ws + 16777216;          // 262,144 f
  float* counts = ws + 17039360;          // 8,192 f
  int*   idxw   = (int*)(ws + 17047552);  // 262,144 i  (total 69.2 MB)

  // c2 table + thresholds live in the quantized output region as scratch;
  // k2 is the only consumer, and gemm2 (last kernel) overwrites the region.
  float* c2tab = quantized;               // 8,192 f
  float* thrv  = quantized + 8192;        // 16 f

  hipLaunchKernelGGL(k_zero, dim3(32), dim3(256), 0, stream, counts, NGRP * NCODE);
  hipLaunchKernelGGL(k_c2, dim3(16), dim3(512), 0, stream, codebooks, c2tab, thrv);
  hipLaunchKernelGGL(gemm_nt, dim3(128, 16), dim3(256), 0, stream,
                     features, Wq, bq, q, (const float*)nullptr, (const int*)nullptr, q2w);
  hipLaunchKernelGGL(k2_select, dim3(4096, 16), dim3(256), 0, stream,
                     q, q2w, codebooks, c2tab, thrv, counts, idxw);
  hipLaunchKernelGGL(k_targets, dim3(64), dim3(256), 0, stream, idxw, targets);
  hipLaunchKernelGGL(k_losses, dim3(1), dim3(512), 0, stream, counts, losses);
  hipLaunchKernelGGL(gemm_nt, dim3(128, 16), dim3(256), 0, stream,
                     (const float*)nullptr, Wout, bout, quantized, codebooks, idxw,
                     (float*)nullptr);
}